// Round 9
// baseline (381.944 us; speedup 1.0000x reference)
//
#include <hip/hip_runtime.h>
#include <cstdint>
#include <cstddef>

typedef unsigned short u16;
typedef __attribute__((ext_vector_type(8))) short bf16x8;
typedef __attribute__((ext_vector_type(4))) float f32x4;

#define MFMA32(a, b, c) __builtin_amdgcn_mfma_f32_16x16x32_bf16(a, b, c, 0, 0, 0)

__device__ __forceinline__ u16 f2b(float f) {
  union { float f; unsigned u; } v; v.f = f;
  unsigned u = v.u;
  return (u16)((u + 0x7fffu + ((u >> 16) & 1u)) >> 16);
}
__device__ __forceinline__ float b2f(u16 h) {
  union { unsigned u; float f; } v; v.u = ((unsigned)h) << 16;
  return v.f;
}

// async global->LDS, 16B per lane. LDS dest must be wave-uniform base + lane*16.
__device__ __forceinline__ void g2l16(const void* g, void* l) {
  __builtin_amdgcn_global_load_lds((__attribute__((address_space(1))) void*)(g),
                                   (__attribute__((address_space(3))) void*)(l), 16, 0, 0);
}

// ---------------- fp32 -> bf16 cast (vectorized x4) ----------------
__global__ __launch_bounds__(256) void cast_f2b_v4(const float* __restrict__ in,
                                                   u16* __restrict__ out, int n4) {
  int i = blockIdx.x * 256 + threadIdx.x;
  if (i >= n4) return;
  float4 v = ((const float4*)in)[i];
  ushort4 r;
  r.x = f2b(v.x); r.y = f2b(v.y); r.z = f2b(v.z); r.w = f2b(v.w);
  ((ushort4*)out)[i] = r;
}

// ---------------- all weight casts in ONE launch ----------------
__global__ __launch_bounds__(256) void cast_weights(const float* __restrict__ W0,
                                                    const float* __restrict__ W1,
                                                    const float* __restrict__ W2,
                                                    const float* __restrict__ W3,
                                                    const float* __restrict__ Wv,
                                                    const float* __restrict__ Wo,
                                                    u16* __restrict__ Wall,
                                                    u16* __restrict__ Wob) {
  const int blk = blockIdx.x;
  const float* src;
  u16* dst;
  int li;
  if (blk < 8192) {
    const int s = blk >> 11;  // uniform per block
    src = s == 0 ? W0 : s == 1 ? W1 : s == 2 ? W2 : W3;
    dst = Wall + (size_t)s * 2097152;
    li = (blk & 2047) * 256 + threadIdx.x;
  } else if (blk < 12288) {
    src = Wv;
    dst = Wall + (size_t)4 * 2097152;
    li = (blk - 8192) * 256 + threadIdx.x;
  } else {
    src = Wo;
    dst = Wob;
    li = (blk - 12288) * 256 + threadIdx.x;
  }
  float4 v = ((const float4*)src)[li];
  ushort4 r;
  r.x = f2b(v.x); r.y = f2b(v.y); r.z = f2b(v.z); r.w = f2b(v.w);
  ((ushort4*)dst)[li] = r;
}

// ---------------- C = A @ B^T  128x128 tile (m97 structure; final projection) -
template <bool BF16_OUT>
__global__ __launch_bounds__(256) void gemm_bt(const u16* __restrict__ A,
                                               const u16* __restrict__ B,
                                               void* __restrict__ C, int N, int K) {
  __shared__ u16 As[128 * 64];
  __shared__ u16 Bs[128 * 64];
  const int tid = threadIdx.x;
  const int wid = tid >> 6;
  const int lane = tid & 63;
  const int lm = lane & 15;
  const int quad = lane >> 4;
  const int r3 = lm & 7;
  const int wm = (wid & 1) * 64;
  const int wn = (wid >> 1) * 64;
  const int bm = blockIdx.y * 128;
  const int bn = blockIdx.x * 128;

  const u16* Ab = A + (size_t)bm * K;
  const u16* Bb = B + (size_t)bn * K;

  f32x4 zero = {0.f, 0.f, 0.f, 0.f};
  f32x4 acc[4][4];
#pragma unroll
  for (int i = 0; i < 4; ++i)
#pragma unroll
    for (int j = 0; j < 4; ++j) acc[i][j] = zero;

  for (int k0 = 0; k0 < K; k0 += 64) {
#pragma unroll
    for (int it = 0; it < 4; ++it) {
      int c = it * 256 + tid;
      int rg = c >> 6, rw = (c >> 3) & 7, u = c & 7;
      int row = rg * 8 + rw;
      int chd = u ^ rw;
      g2l16(Ab + (size_t)row * K + k0 + chd * 8, As + c * 8);
      g2l16(Bb + (size_t)row * K + k0 + chd * 8, Bs + c * 8);
    }
    __syncthreads();
#pragma unroll
    for (int ks = 0; ks < 2; ++ks) {
      bf16x8 a[4], b[4];
      int chd = ks * 4 + quad;
#pragma unroll
      for (int i = 0; i < 4; ++i) {
        int row = wm + i * 16 + lm;
        a[i] = *(const bf16x8*)(As + (((row >> 3) * 64 + r3 * 8 + (chd ^ r3)) * 8));
      }
#pragma unroll
      for (int j = 0; j < 4; ++j) {
        int row = wn + j * 16 + lm;
        b[j] = *(const bf16x8*)(Bs + (((row >> 3) * 64 + r3 * 8 + (chd ^ r3)) * 8));
      }
#pragma unroll
      for (int i = 0; i < 4; ++i)
#pragma unroll
        for (int j = 0; j < 4; ++j)
          acc[i][j] = MFMA32(a[i], b[j], acc[i][j]);
    }
    __syncthreads();
  }

#pragma unroll
  for (int i = 0; i < 4; ++i)
#pragma unroll
    for (int j = 0; j < 4; ++j)
#pragma unroll
      for (int r = 0; r < 4; ++r) {
        int row = bm + wm + i * 16 + quad * 4 + r;
        int col = bn + wn + j * 16 + lm;
        float v = acc[i][j][r];
        if (BF16_OUT)
          ((u16*)C)[(size_t)row * N + col] = f2b(v);
        else
          ((float*)C)[(size_t)row * N + col] = v;
      }
}

// ---------------- QKV GEMM with fused RoPE/rearrange epilogue v2 --------------
// R8's epilogue cost ~15us: sem/geo did 64 scalar 2B global stores/thread, and
// the V-transpose LDS buffer (stride 66) had a 4-way read conflict (1.05M
// counted). v2: ALL paths stage their 128x128 output tile into the dead As/Bs
// LDS as an XOR-chunk-swizzled [128][128] (32KB exactly, same swizzle family
// as the main loop = 0-conflict), then write globals as coalesced 16B bf16x8
// rows: 8 x (ds_read_b128 + 16B store)/thread. Global-store instrs 64 -> 8.
__global__ __launch_bounds__(256) void gemm_qkv(const u16* __restrict__ A,
                                                const u16* __restrict__ B,
                                                u16* __restrict__ Qb,
                                                u16* __restrict__ Kb,
                                                u16* __restrict__ VT) {
  constexpr int K = 2048;
  const float SC = 0.12751744f;  // (1/sqrt(128)) * log2(e)
  __shared__ u16 sh[16384];      // As | Bs, reused as swizzled 128x128 out tile
  u16* As = sh;
  u16* Bs = sh + 8192;
  const int tid = threadIdx.x;
  const int wid = tid >> 6;
  const int lane = tid & 63;
  const int lm = lane & 15;
  const int quad = lane >> 4;
  const int r3 = lm & 7;
  const int wm = (wid & 1) * 64;
  const int wn = (wid >> 1) * 64;
  const int bm = blockIdx.y * 128;
  const int bn = blockIdx.x * 128;

  const u16* Ab = A + (size_t)bm * K;
  const u16* Bb = B + (size_t)bn * K;

  f32x4 zero = {0.f, 0.f, 0.f, 0.f};
  f32x4 acc[4][4];
#pragma unroll
  for (int i = 0; i < 4; ++i)
#pragma unroll
    for (int j = 0; j < 4; ++j) acc[i][j] = zero;

  for (int k0 = 0; k0 < K; k0 += 64) {
#pragma unroll
    for (int it = 0; it < 4; ++it) {
      int c = it * 256 + tid;
      int rg = c >> 6, rw = (c >> 3) & 7, u = c & 7;
      int row = rg * 8 + rw;
      int chd = u ^ rw;
      g2l16(Ab + (size_t)row * K + k0 + chd * 8, As + c * 8);
      g2l16(Bb + (size_t)row * K + k0 + chd * 8, Bs + c * 8);
    }
    __syncthreads();
#pragma unroll
    for (int ks = 0; ks < 2; ++ks) {
      bf16x8 a[4], b[4];
      int chd = ks * 4 + quad;
#pragma unroll
      for (int i = 0; i < 4; ++i) {
        int row = wm + i * 16 + lm;
        a[i] = *(const bf16x8*)(As + (((row >> 3) * 64 + r3 * 8 + (chd ^ r3)) * 8));
      }
#pragma unroll
      for (int j = 0; j < 4; ++j) {
        int row = wn + j * 16 + lm;
        b[j] = *(const bf16x8*)(Bs + (((row >> 3) * 64 + r3 * 8 + (chd ^ r3)) * 8));
      }
#pragma unroll
      for (int i = 0; i < 4; ++i)
#pragma unroll
        for (int j = 0; j < 4; ++j)
          acc[i][j] = MFMA32(a[i], b[j], acc[i][j]);
    }
    __syncthreads();
  }

  const int seg = bn >> 10;       // uniform per block
  const int b = bm >> 11;
  const int sbase = bm & 2047;

  if (seg < 4) {
    // ---- Q/K (sem direct, geo roped in f32 regs) -> swizzled [s][col] tile --
    const bool isQ = (seg == 0) || (seg == 2);
    const bool geo = (seg >= 2);
    u16* dst = isQ ? Qb : Kb;
    const float sc = isQ ? SC : 1.0f;
    if (!geo) {
#pragma unroll
      for (int i = 0; i < 4; ++i)
#pragma unroll
        for (int r = 0; r < 4; ++r) {
          const int rl = wm + i * 16 + quad * 4 + r;
          const int r7 = rl & 7;
#pragma unroll
          for (int j = 0; j < 4; ++j) {
            const int lc = wn + j * 16 + lm;
            sh[rl * 128 + (((lc >> 3) ^ r7) << 3) + (lc & 7)] = f2b(acc[i][j][r] * sc);
          }
        }
    } else {
      // RoPE pairs (f0, f0+32) are acc[i][j]/acc[i][j+2] of the SAME thread.
      const float inv0 = __powf(10000.0f, -(float)(2 * lm) * (1.0f / 64.0f));
      const float inv1 = __powf(10000.0f, -(float)(2 * (16 + lm)) * (1.0f / 64.0f));
#pragma unroll
      for (int i = 0; i < 4; ++i)
#pragma unroll
        for (int r = 0; r < 4; ++r) {
          const int rl = wm + i * 16 + quad * 4 + r;
          const int r7 = rl & 7;
          const int s = sbase + rl;
          float sn0, cs0, sn1, cs1;
          __sincosf((float)s * inv0, &sn0, &cs0);
          __sincosf((float)s * inv1, &sn1, &cs1);
          const float x1a = acc[i][0][r], x2a = acc[i][2][r];  // f0 = lm
          const float x1b = acc[i][1][r], x2b = acc[i][3][r];  // f0 = 16+lm
          u16* row = sh + rl * 128;
          int lc;
          lc = wn + lm;      row[(((lc >> 3) ^ r7) << 3) + (lc & 7)] = f2b((x1a * cs0 - x2a * sn0) * sc);
          lc = wn + 16 + lm; row[(((lc >> 3) ^ r7) << 3) + (lc & 7)] = f2b((x1b * cs1 - x2b * sn1) * sc);
          lc = wn + 32 + lm; row[(((lc >> 3) ^ r7) << 3) + (lc & 7)] = f2b((x1a * sn0 + x2a * cs0) * sc);
          lc = wn + 48 + lm; row[(((lc >> 3) ^ r7) << 3) + (lc & 7)] = f2b((x1b * sn1 + x2b * cs1) * sc);
        }
    }
    __syncthreads();
    // writer: 8 x (b128 LDS read + coalesced 16B store)
    const int segbase = bn & 1023;
    const int dof = geo ? 64 : 0;
#pragma unroll
    for (int it = 0; it < 8; ++it) {
      const int idx = it * 256 + tid;
      const int rl = idx >> 4;     // 0..127
      const int ch = idx & 15;     // 8-u16 chunk within row
      bf16x8 v = *(const bf16x8*)(sh + rl * 128 + ((ch ^ (rl & 7)) << 3));
      const int segcol = segbase + ch * 8;
      const int h = segcol >> 6;
      const int d0 = dof + (segcol & 63);
      *(bf16x8*)(dst + ((size_t)(b * 16 + h) * 2048 + sbase + rl) * 128 + d0) = v;
    }
  } else {
    // ---- V: stage TRANSPOSED [d][s] swizzled, write coalesced VT rows -------
    const int hv = (bn - 4096) >> 7;   // one head per tile
    const size_t bh = (size_t)b * 16 + hv;
#pragma unroll
    for (int i = 0; i < 4; ++i)
#pragma unroll
      for (int r = 0; r < 4; ++r) {
        const int sr = wm + i * 16 + quad * 4 + r;
#pragma unroll
        for (int j = 0; j < 4; ++j) {
          const int d = wn + j * 16 + lm;
          sh[d * 128 + (((sr >> 3) ^ (d & 7)) << 3) + (sr & 7)] = f2b(acc[i][j][r]);
        }
      }
    __syncthreads();
#pragma unroll
    for (int it = 0; it < 8; ++it) {
      const int idx = it * 256 + tid;
      const int d = idx >> 4;      // 0..127
      const int ch = idx & 15;     // 8-s chunk
      bf16x8 v = *(const bf16x8*)(sh + d * 128 + ((ch ^ (d & 7)) << 3));
      *(bf16x8*)(VT + (bh * 128 + d) * 2048 + sbase + ch * 8) = v;
    }
  }
}

// ---------------- fused causal attention v8 (R6-passed: XCD-affinity remap) ---
__global__ __launch_bounds__(256, 2) void attn_v8(const u16* __restrict__ Q,
                                                  const u16* __restrict__ K,
                                                  const u16* __restrict__ VT,
                                                  u16* __restrict__ O) {
  constexpr int S = 2048;
  constexpr int D = 128;
  __shared__ u16 Ks[2][64 * 128];  // chunk-swizzled
  __shared__ u16 Vs[2][128 * 64];  // VT tile [d][s_local], chunk-swizzled
  __shared__ u16 Ps[64 * 72];      // wave-private rows; padded stride 72
  const int linear = blockIdx.x + (blockIdx.y << 4);
  const int xcd = linear & 7;
  const int slot = linear >> 3;          // 0..63
  const int bh = (xcd << 2) + (slot >> 4);
  const int bx = slot & 15;
  const int b = bh >> 4, h = bh & 15;
  const int tid = threadIdx.x, wid = tid >> 6, lane = tid & 63;
  const int lm = lane & 15, quad = lane >> 4;
  const int rx = lm & 7;
  const int wrow = wid * 16;

  const u16* Kbh = K + (size_t)bh * S * D;
  const u16* Vbh = VT + (size_t)bh * D * S;

  auto stageKV = [&](int kt, int bufid) {
    const u16* Kt = Kbh + (size_t)kt * 64 * D;
    const u16* Vt = Vbh + (size_t)kt * 64;
#pragma unroll
    for (int it = 0; it < 4; ++it) {
      int c = it * 256 + tid;
      int row = c >> 4, u = c & 15;
      g2l16(Kt + (size_t)row * 128 + (size_t)(u ^ (row & 7)) * 8, &Ks[bufid][c * 8]);
    }
#pragma unroll
    for (int it = 0; it < 4; ++it) {
      int c = it * 256 + tid;
      int row = c >> 3, u = c & 7;
      g2l16(Vt + (size_t)row * S + (size_t)(u ^ (row & 7)) * 8, &Vs[bufid][c * 8]);
    }
  };

#pragma unroll 1
  for (int pass = 0; pass < 2; ++pass) {
    const int qt = pass == 0 ? bx : 31 - bx;

    bf16x8 aq[4];
#pragma unroll
    for (int ks = 0; ks < 4; ++ks)
      aq[ks] = *(const bf16x8*)(Q + ((size_t)bh * S + (size_t)qt * 64 + wrow + lm) * D +
                                ks * 32 + quad * 8);

    float l_r[4] = {0.f, 0.f, 0.f, 0.f};
    f32x4 zero = {0.f, 0.f, 0.f, 0.f};
    f32x4 oacc[8];
#pragma unroll
    for (int t = 0; t < 8; ++t) oacc[t] = zero;

    stageKV(0, 0);
    asm volatile("s_waitcnt vmcnt(0)" ::: "memory");
    __builtin_amdgcn_s_barrier();

#pragma unroll 1
    for (int kt = 0; kt <= qt; ++kt) {
      const int cur = kt & 1;
      if (kt < qt) stageKV(kt + 1, cur ^ 1);

      f32x4 sc[4];
#pragma unroll
      for (int j = 0; j < 4; ++j) sc[j] = zero;
      __builtin_amdgcn_s_setprio(1);
#pragma unroll
      for (int ks = 0; ks < 4; ++ks) {
        const int kc = ks * 4 + quad;
#pragma unroll
        for (int j = 0; j < 4; ++j) {
          bf16x8 bk = *(const bf16x8*)(&Ks[cur][((j * 16 + lm) * 16 + (kc ^ rx)) * 8]);
          sc[j] = MFMA32(aq[ks], bk, sc[j]);
        }
      }
      __builtin_amdgcn_s_setprio(0);

      const bool diag = (kt == qt);
#pragma unroll
      for (int r = 0; r < 4; ++r) {
        const int qcol = wrow + quad * 4 + r;
        float pv[4];
        float rs = 0.f;
#pragma unroll
        for (int j = 0; j < 4; ++j) {
          float p = __builtin_amdgcn_exp2f(fminf(sc[j][r], 30.0f));
          if (diag && (j * 16 + lm > qcol)) p = 0.f;
          rs += p;
          pv[j] = p;
        }
#pragma unroll
        for (int dd = 1; dd < 16; dd <<= 1) rs += __shfl_xor(rs, dd);
        l_r[r] += rs;
        const int prow = (wrow + quad * 4 + r) * 72;
#pragma unroll
        for (int j = 0; j < 4; ++j) Ps[prow + j * 16 + lm] = f2b(pv[j]);
      }

      __builtin_amdgcn_s_setprio(1);
#pragma unroll
      for (int ks = 0; ks < 2; ++ks) {
        bf16x8 ap = *(const bf16x8*)(Ps + (wrow + lm) * 72 + ks * 32 + quad * 8);
        const int kc = ks * 4 + quad;
#pragma unroll
        for (int t = 0; t < 8; ++t) {
          bf16x8 bv = *(const bf16x8*)(&Vs[cur][((t * 16 + lm) * 8 + (kc ^ rx)) * 8]);
          oacc[t] = MFMA32(ap, bv, oacc[t]);
        }
      }
      __builtin_amdgcn_s_setprio(0);

      if (kt < qt) asm volatile("s_waitcnt vmcnt(0)" ::: "memory");
      __builtin_amdgcn_s_barrier();
    }

#pragma unroll
    for (int r = 0; r < 4; ++r) {
      float inv = 1.0f / l_r[r];
      const int srow = qt * 64 + wrow + quad * 4 + r;
      u16* Orow = O + ((size_t)b * S + srow) * 2048 + h * 128;
#pragma unroll
      for (int t = 0; t < 8; ++t) Orow[t * 16 + lm] = f2b(oacc[t][r] * inv);
    }
  }
}

extern "C" void kernel_launch(void* const* d_in, const int* in_sizes, int n_in,
                              void* d_out, int out_size, void* d_ws, size_t ws_size,
                              hipStream_t stream) {
  const float* x      = (const float*)d_in[0];
  const float* Wq_sem = (const float*)d_in[1];
  const float* Wk_sem = (const float*)d_in[2];
  const float* Wq_geo = (const float*)d_in[3];
  const float* Wk_geo = (const float*)d_in[4];
  const float* Wv     = (const float*)d_in[5];
  const float* Wo     = (const float*)d_in[6];

  char* ws = (char*)d_ws;
  // layout (bytes):
  //   [0, 16M)          xb  (x bf16, 4096x2048)
  //   [16M, 41.2M)      Wall (6144x2048 bf16)   -> later reused as O
  //   [41.2M, 49.6M)    Wob  (2048x2048 bf16)
  //   [49.6M, 66.3M)    Qb   (bf16, 32 heads x 2048 x 128)
  // d_out (33.5MB) used as scratch for K (16.7M) + VT (16.7M) until final GEMM.
  u16* xb   = (u16*)(ws);
  u16* Wall = (u16*)(ws + 16777216);
  u16* Wob  = (u16*)(ws + 16777216 + 25165824);
  u16* Qb   = (u16*)(ws + 16777216 + 25165824 + 8388608);
  u16* Ob   = Wall;
  u16* Kb   = (u16*)d_out;
  u16* VT   = (u16*)((char*)d_out + 16777216);

  // casts to bf16 (2 launches)
  cast_f2b_v4<<<8192, 256, 0, stream>>>(x, xb, 2097152);
  cast_weights<<<16384, 256, 0, stream>>>(Wq_sem, Wk_sem, Wq_geo, Wk_geo, Wv, Wo, Wall, Wob);

  // fused QKV projection + RoPE + head rearrange: writes Q/K/VT directly
  gemm_qkv<<<dim3(48, 32), 256, 0, stream>>>(xb, Wall, Qb, Kb, VT);

  // causal flash attention -> O (B*S, 2048) bf16
  attn_v8<<<dim3(16, 32), 256, 0, stream>>>(Qb, Kb, VT, Ob);

  // final projection: out = O @ Wo^T  (M=4096, N=2048, K=2048), fp32 out
  gemm_bt<false><<<dim3(16, 32), 256, 0, stream>>>(Ob, Wob, d_out, 2048, 2048);
}

// Round 10
// 357.576 us; speedup vs baseline: 1.0681x; 1.0681x over previous
//
#include <hip/hip_runtime.h>
#include <cstdint>
#include <cstddef>

typedef unsigned short u16;
typedef __attribute__((ext_vector_type(8))) short bf16x8;
typedef __attribute__((ext_vector_type(4))) float f32x4;

#define MFMA32(a, b, c) __builtin_amdgcn_mfma_f32_16x16x32_bf16(a, b, c, 0, 0, 0)

__device__ __forceinline__ u16 f2b(float f) {
  union { float f; unsigned u; } v; v.f = f;
  unsigned u = v.u;
  return (u16)((u + 0x7fffu + ((u >> 16) & 1u)) >> 16);
}
__device__ __forceinline__ float b2f(u16 h) {
  union { unsigned u; float f; } v; v.u = ((unsigned)h) << 16;
  return v.f;
}

// async global->LDS, 16B per lane. LDS dest must be wave-uniform base + lane*16.
__device__ __forceinline__ void g2l16(const void* g, void* l) {
  __builtin_amdgcn_global_load_lds((__attribute__((address_space(1))) void*)(g),
                                   (__attribute__((address_space(3))) void*)(l), 16, 0, 0);
}

// ---------------- ALL fp32->bf16 casts in one launch --------------------------
// blocks 0..8191: x -> xb; 8192..16383: W0..W3 -> Wall[0..3];
// 16384..20479: Wv -> Wall[4]; 20480..24575: Wo -> Wob.
__global__ __launch_bounds__(256) void cast_all(const float* __restrict__ x,
                                                const float* __restrict__ W0,
                                                const float* __restrict__ W1,
                                                const float* __restrict__ W2,
                                                const float* __restrict__ W3,
                                                const float* __restrict__ Wv,
                                                const float* __restrict__ Wo,
                                                u16* __restrict__ xb,
                                                u16* __restrict__ Wall,
                                                u16* __restrict__ Wob) {
  const int blk = blockIdx.x;
  const float* src;
  u16* dst;
  int li;
  if (blk < 8192) {
    src = x; dst = xb; li = blk * 256 + threadIdx.x;
  } else if (blk < 16384) {
    const int s = (blk - 8192) >> 11;
    src = s == 0 ? W0 : s == 1 ? W1 : s == 2 ? W2 : W3;
    dst = Wall + (size_t)s * 2097152;
    li = ((blk - 8192) & 2047) * 256 + threadIdx.x;
  } else if (blk < 20480) {
    src = Wv; dst = Wall + (size_t)4 * 2097152;
    li = (blk - 16384) * 256 + threadIdx.x;
  } else {
    src = Wo; dst = Wob;
    li = (blk - 20480) * 256 + threadIdx.x;
  }
  float4 v = ((const float4*)src)[li];
  ushort4 r;
  r.x = f2b(v.x); r.y = f2b(v.y); r.z = f2b(v.z); r.w = f2b(v.w);
  ((ushort4*)dst)[li] = r;
}

// ---------------- C = A @ B^T  128x128 tile (m97 structure; final projection) -
template <bool BF16_OUT>
__global__ __launch_bounds__(256) void gemm_bt(const u16* __restrict__ A,
                                               const u16* __restrict__ B,
                                               void* __restrict__ C, int N, int K) {
  __shared__ u16 As[128 * 64];
  __shared__ u16 Bs[128 * 64];
  const int tid = threadIdx.x;
  const int wid = tid >> 6;
  const int lane = tid & 63;
  const int lm = lane & 15;
  const int quad = lane >> 4;
  const int r3 = lm & 7;
  const int wm = (wid & 1) * 64;
  const int wn = (wid >> 1) * 64;
  const int bm = blockIdx.y * 128;
  const int bn = blockIdx.x * 128;

  const u16* Ab = A + (size_t)bm * K;
  const u16* Bb = B + (size_t)bn * K;

  f32x4 zero = {0.f, 0.f, 0.f, 0.f};
  f32x4 acc[4][4];
#pragma unroll
  for (int i = 0; i < 4; ++i)
#pragma unroll
    for (int j = 0; j < 4; ++j) acc[i][j] = zero;

  for (int k0 = 0; k0 < K; k0 += 64) {
#pragma unroll
    for (int it = 0; it < 4; ++it) {
      int c = it * 256 + tid;
      int rg = c >> 6, rw = (c >> 3) & 7, u = c & 7;
      int row = rg * 8 + rw;
      int chd = u ^ rw;
      g2l16(Ab + (size_t)row * K + k0 + chd * 8, As + c * 8);
      g2l16(Bb + (size_t)row * K + k0 + chd * 8, Bs + c * 8);
    }
    __syncthreads();
#pragma unroll
    for (int ks = 0; ks < 2; ++ks) {
      bf16x8 a[4], b[4];
      int chd = ks * 4 + quad;
#pragma unroll
      for (int i = 0; i < 4; ++i) {
        int row = wm + i * 16 + lm;
        a[i] = *(const bf16x8*)(As + (((row >> 3) * 64 + r3 * 8 + (chd ^ r3)) * 8));
      }
#pragma unroll
      for (int j = 0; j < 4; ++j) {
        int row = wn + j * 16 + lm;
        b[j] = *(const bf16x8*)(Bs + (((row >> 3) * 64 + r3 * 8 + (chd ^ r3)) * 8));
      }
#pragma unroll
      for (int i = 0; i < 4; ++i)
#pragma unroll
        for (int j = 0; j < 4; ++j)
          acc[i][j] = MFMA32(a[i], b[j], acc[i][j]);
    }
    __syncthreads();
  }

#pragma unroll
  for (int i = 0; i < 4; ++i)
#pragma unroll
    for (int j = 0; j < 4; ++j)
#pragma unroll
      for (int r = 0; r < 4; ++r) {
        int row = bm + wm + i * 16 + quad * 4 + r;
        int col = bn + wn + j * 16 + lm;
        float v = acc[i][j][r];
        if (BF16_OUT)
          ((u16*)C)[(size_t)row * N + col] = f2b(v);
        else
          ((float*)C)[(size_t)row * N + col] = v;
      }
}

// ---------------- QKV GEMM with fused RoPE/rearrange epilogue v3 (hybrid) -----
// R8-v1 (direct scalar stores) cost was in the V-transpose LDS conflicts, not
// the sem/geo stores (gemm_bt does identical stores at 119us). R9-v2 (stage
// everything) added 64 ds_writes to all paths: net slower. v3 hybrid:
//  - sem/geo: v1 direct global scalar stores (proven epilogue cost);
//  - V: v2 swizzled [d][s] LDS staging + coalesced bf16x8 row writes
//    (fixes the 1.05M 4-way conflicts of the stride-66 buffer).
__global__ __launch_bounds__(256) void gemm_qkv(const u16* __restrict__ A,
                                                const u16* __restrict__ B,
                                                u16* __restrict__ Qb,
                                                u16* __restrict__ Kb,
                                                u16* __restrict__ VT) {
  constexpr int K = 2048;
  const float SC = 0.12751744f;  // (1/sqrt(128)) * log2(e)
  __shared__ u16 sh[16384];      // As | Bs, reused for V staging
  u16* As = sh;
  u16* Bs = sh + 8192;
  const int tid = threadIdx.x;
  const int wid = tid >> 6;
  const int lane = tid & 63;
  const int lm = lane & 15;
  const int quad = lane >> 4;
  const int r3 = lm & 7;
  const int wm = (wid & 1) * 64;
  const int wn = (wid >> 1) * 64;
  const int bm = blockIdx.y * 128;
  const int bn = blockIdx.x * 128;

  const u16* Ab = A + (size_t)bm * K;
  const u16* Bb = B + (size_t)bn * K;

  f32x4 zero = {0.f, 0.f, 0.f, 0.f};
  f32x4 acc[4][4];
#pragma unroll
  for (int i = 0; i < 4; ++i)
#pragma unroll
    for (int j = 0; j < 4; ++j) acc[i][j] = zero;

  for (int k0 = 0; k0 < K; k0 += 64) {
#pragma unroll
    for (int it = 0; it < 4; ++it) {
      int c = it * 256 + tid;
      int rg = c >> 6, rw = (c >> 3) & 7, u = c & 7;
      int row = rg * 8 + rw;
      int chd = u ^ rw;
      g2l16(Ab + (size_t)row * K + k0 + chd * 8, As + c * 8);
      g2l16(Bb + (size_t)row * K + k0 + chd * 8, Bs + c * 8);
    }
    __syncthreads();
#pragma unroll
    for (int ks = 0; ks < 2; ++ks) {
      bf16x8 a[4], b[4];
      int chd = ks * 4 + quad;
#pragma unroll
      for (int i = 0; i < 4; ++i) {
        int row = wm + i * 16 + lm;
        a[i] = *(const bf16x8*)(As + (((row >> 3) * 64 + r3 * 8 + (chd ^ r3)) * 8));
      }
#pragma unroll
      for (int j = 0; j < 4; ++j) {
        int row = wn + j * 16 + lm;
        b[j] = *(const bf16x8*)(Bs + (((row >> 3) * 64 + r3 * 8 + (chd ^ r3)) * 8));
      }
#pragma unroll
      for (int i = 0; i < 4; ++i)
#pragma unroll
        for (int j = 0; j < 4; ++j)
          acc[i][j] = MFMA32(a[i], b[j], acc[i][j]);
    }
    __syncthreads();
  }

  const int seg = bn >> 10;       // uniform per block
  const int b = bm >> 11;
  const int sbase = bm & 2047;
  const int h = ((bn + wn) >> 6) & 15;  // head for Q/K segments
  const size_t bhQ = (size_t)b * 16 + h;

  if (seg < 2) {
    // ---- sem: direct copy (v1) ----
    u16* dst = (seg == 0) ? Qb : Kb;
    const float sc = (seg == 0) ? SC : 1.0f;
#pragma unroll
    for (int i = 0; i < 4; ++i)
#pragma unroll
      for (int r = 0; r < 4; ++r) {
        const int s = sbase + wm + i * 16 + quad * 4 + r;
        u16* base = dst + (bhQ * 2048 + s) * 128;
#pragma unroll
        for (int j = 0; j < 4; ++j) {
          const int d = (wn + j * 16 + lm) & 63;
          base[d] = f2b(acc[i][j][r] * sc);
        }
      }
  } else if (seg < 4) {
    // ---- geo: RoPE in-register, write d in [64,128) (v1) ----
    u16* dst = (seg == 2) ? Qb : Kb;
    const float sc = (seg == 2) ? SC : 1.0f;
    const float inv0 = __powf(10000.0f, -(float)(2 * lm) * (1.0f / 64.0f));
    const float inv1 = __powf(10000.0f, -(float)(2 * (16 + lm)) * (1.0f / 64.0f));
#pragma unroll
    for (int i = 0; i < 4; ++i)
#pragma unroll
      for (int r = 0; r < 4; ++r) {
        const int s = sbase + wm + i * 16 + quad * 4 + r;
        float sn0, cs0, sn1, cs1;
        __sincosf((float)s * inv0, &sn0, &cs0);
        __sincosf((float)s * inv1, &sn1, &cs1);
        const float x1a = acc[i][0][r], x2a = acc[i][2][r];  // f0 = lm
        const float x1b = acc[i][1][r], x2b = acc[i][3][r];  // f0 = 16+lm
        u16* base = dst + (bhQ * 2048 + s) * 128 + 64;
        base[lm]      = f2b((x1a * cs0 - x2a * sn0) * sc);
        base[16 + lm] = f2b((x1b * cs1 - x2b * sn1) * sc);
        base[32 + lm] = f2b((x1a * sn0 + x2a * cs0) * sc);
        base[48 + lm] = f2b((x1b * sn1 + x2b * cs1) * sc);
      }
  } else {
    // ---- V: stage TRANSPOSED [d][s] swizzled, write coalesced VT rows (v2) --
    const int hv = (bn - 4096) >> 7;   // one head per tile
    const size_t bh = (size_t)b * 16 + hv;
#pragma unroll
    for (int i = 0; i < 4; ++i)
#pragma unroll
      for (int r = 0; r < 4; ++r) {
        const int sr = wm + i * 16 + quad * 4 + r;
#pragma unroll
        for (int j = 0; j < 4; ++j) {
          const int d = wn + j * 16 + lm;
          sh[d * 128 + (((sr >> 3) ^ (d & 7)) << 3) + (sr & 7)] = f2b(acc[i][j][r]);
        }
      }
    __syncthreads();
#pragma unroll
    for (int it = 0; it < 8; ++it) {
      const int idx = it * 256 + tid;
      const int d = idx >> 4;      // 0..127
      const int ch = idx & 15;     // 8-s chunk
      bf16x8 v = *(const bf16x8*)(sh + d * 128 + ((ch ^ (d & 7)) << 3));
      *(bf16x8*)(VT + (bh * 128 + d) * 2048 + sbase + ch * 8) = v;
    }
  }
}

// ---------------- fused causal attention v9 -----------------------------------
// v8 + two changes:
//  (1) single-buffer K/V (41KB) @ 3 blocks/CU: with K/V L2-resident after the
//      XCD remap, dbuf's latency hiding was worth ~nothing (R5: dbuf==single);
//      12 waves/CU instead of 8 overlaps the softmax VALU phase better.
//  (2) softmax row-sum via MFMA with a constant all-ones B fragment
//      (P @ ones == rowsum; all-ones is layout-invariant; same A operand as
//      PV so lsum[r] lands where l_r[r] lived). Removes 16 shfl_xor + 16 adds
//      per iteration from the VALU critical path; lsum accumulates across kt.
__global__ __launch_bounds__(256, 3) void attn_v9(const u16* __restrict__ Q,
                                                  const u16* __restrict__ K,
                                                  const u16* __restrict__ VT,
                                                  u16* __restrict__ O) {
  constexpr int S = 2048;
  constexpr int D = 128;
  __shared__ u16 Ks[64 * 128];  // chunk-swizzled
  __shared__ u16 Vs[128 * 64];  // VT tile [d][s_local], chunk-swizzled
  __shared__ u16 Ps[64 * 72];   // wave-private rows; padded stride 72
  const int linear = blockIdx.x + (blockIdx.y << 4);
  const int xcd = linear & 7;
  const int slot = linear >> 3;          // 0..63
  const int bh = (xcd << 2) + (slot >> 4);
  const int bx = slot & 15;
  const int b = bh >> 4, h = bh & 15;
  const int tid = threadIdx.x, wid = tid >> 6, lane = tid & 63;
  const int lm = lane & 15, quad = lane >> 4;
  const int rx = lm & 7;
  const int wrow = wid * 16;

  const u16* Kbh = K + (size_t)bh * S * D;
  const u16* Vbh = VT + (size_t)bh * D * S;

  const bf16x8 vones = {16256, 16256, 16256, 16256, 16256, 16256, 16256, 16256};  // bf16 1.0

#pragma unroll 1
  for (int pass = 0; pass < 2; ++pass) {
    const int qt = pass == 0 ? bx : 31 - bx;

    bf16x8 aq[4];
#pragma unroll
    for (int ks = 0; ks < 4; ++ks)
      aq[ks] = *(const bf16x8*)(Q + ((size_t)bh * S + (size_t)qt * 64 + wrow + lm) * D +
                                ks * 32 + quad * 8);

    f32x4 zero = {0.f, 0.f, 0.f, 0.f};
    f32x4 lsum = zero;
    f32x4 oacc[8];
#pragma unroll
    for (int t = 0; t < 8; ++t) oacc[t] = zero;

#pragma unroll 1
    for (int kt = 0; kt <= qt; ++kt) {
      __syncthreads();  // prior iteration's readers done with Ks/Vs
      const u16* Kt = Kbh + (size_t)kt * 64 * D;
      const u16* Vt = Vbh + (size_t)kt * 64;
#pragma unroll
      for (int it = 0; it < 4; ++it) {
        int c = it * 256 + tid;
        int row = c >> 4, u = c & 15;
        g2l16(Kt + (size_t)row * 128 + (size_t)(u ^ (row & 7)) * 8, Ks + c * 8);
      }
#pragma unroll
      for (int it = 0; it < 4; ++it) {
        int c = it * 256 + tid;
        int row = c >> 3, u = c & 7;
        g2l16(Vt + (size_t)row * S + (size_t)(u ^ (row & 7)) * 8, Vs + c * 8);
      }
      __syncthreads();  // barrier drains vmcnt: staged data visible

      // S-tile = Q K^T
      f32x4 sc[4];
#pragma unroll
      for (int j = 0; j < 4; ++j) sc[j] = zero;
      __builtin_amdgcn_s_setprio(1);
#pragma unroll
      for (int ks = 0; ks < 4; ++ks) {
        const int kc = ks * 4 + quad;
#pragma unroll
        for (int j = 0; j < 4; ++j) {
          bf16x8 bk = *(const bf16x8*)(Ks + (((j * 16 + lm) * 16 + (kc ^ rx)) * 8));
          sc[j] = MFMA32(aq[ks], bk, sc[j]);
        }
      }
      __builtin_amdgcn_s_setprio(0);

      const bool diag = (kt == qt);
#pragma unroll
      for (int r = 0; r < 4; ++r) {
        const int qcol = wrow + quad * 4 + r;
        const int prow = (wrow + quad * 4 + r) * 72;
#pragma unroll
        for (int j = 0; j < 4; ++j) {
          float p = __builtin_amdgcn_exp2f(fminf(sc[j][r], 30.0f));
          if (diag && (j * 16 + lm > qcol)) p = 0.f;
          Ps[prow + j * 16 + lm] = f2b(p);
        }
      }
      // no barrier: Ps rows are wave-private (proven R4)

      // O += P @ V ; row-sum += P @ ones (replaces the shuffle reduce)
      __builtin_amdgcn_s_setprio(1);
#pragma unroll
      for (int ks = 0; ks < 2; ++ks) {
        bf16x8 ap = *(const bf16x8*)(Ps + (wrow + lm) * 72 + ks * 32 + quad * 8);
        const int kc = ks * 4 + quad;
        lsum = MFMA32(ap, vones, lsum);
#pragma unroll
        for (int t = 0; t < 8; ++t) {
          bf16x8 bv = *(const bf16x8*)(Vs + (((t * 16 + lm) * 8 + (kc ^ rx)) * 8));
          oacc[t] = MFMA32(ap, bv, oacc[t]);
        }
      }
      __builtin_amdgcn_s_setprio(0);
    }

#pragma unroll
    for (int r = 0; r < 4; ++r) {
      float inv = 1.0f / lsum[r];
      const int srow = qt * 64 + wrow + quad * 4 + r;
      u16* Orow = O + ((size_t)b * S + srow) * 2048 + h * 128;
#pragma unroll
      for (int t = 0; t < 8; ++t) Orow[t * 16 + lm] = f2b(oacc[t][r] * inv);
    }
  }
}

extern "C" void kernel_launch(void* const* d_in, const int* in_sizes, int n_in,
                              void* d_out, int out_size, void* d_ws, size_t ws_size,
                              hipStream_t stream) {
  const float* x      = (const float*)d_in[0];
  const float* Wq_sem = (const float*)d_in[1];
  const float* Wk_sem = (const float*)d_in[2];
  const float* Wq_geo = (const float*)d_in[3];
  const float* Wk_geo = (const float*)d_in[4];
  const float* Wv     = (const float*)d_in[5];
  const float* Wo     = (const float*)d_in[6];

  char* ws = (char*)d_ws;
  // layout (bytes):
  //   [0, 16M)          xb  (x bf16, 4096x2048)
  //   [16M, 41.2M)      Wall (6144x2048 bf16)   -> later reused as O
  //   [41.2M, 49.6M)    Wob  (2048x2048 bf16)
  //   [49.6M, 66.3M)    Qb   (bf16, 32 heads x 2048 x 128)
  // d_out (33.5MB) used as scratch for K (16.7M) + VT (16.7M) until final GEMM.
  u16* xb   = (u16*)(ws);
  u16* Wall = (u16*)(ws + 16777216);
  u16* Wob  = (u16*)(ws + 16777216 + 25165824);
  u16* Qb   = (u16*)(ws + 16777216 + 25165824 + 8388608);
  u16* Ob   = Wall;
  u16* Kb   = (u16*)d_out;
  u16* VT   = (u16*)((char*)d_out + 16777216);

  // all casts in one launch
  cast_all<<<24576, 256, 0, stream>>>(x, Wq_sem, Wk_sem, Wq_geo, Wk_geo, Wv, Wo,
                                      xb, Wall, Wob);

  // fused QKV projection + RoPE + head rearrange: writes Q/K/VT directly
  gemm_qkv<<<dim3(48, 32), 256, 0, stream>>>(xb, Wall, Qb, Kb, VT);

  // causal flash attention -> O (B*S, 2048) bf16
  attn_v9<<<dim3(16, 32), 256, 0, stream>>>(Qb, Kb, VT, Ob);

  // final projection: out = O @ Wo^T  (M=4096, N=2048, K=2048), fp32 out
  gemm_bt<false><<<dim3(16, 32), 256, 0, stream>>>(Ob, Wob, d_out, 2048, 2048);
}